// Round 1
// baseline (600.653 us; speedup 1.0000x reference)
//
#include <hip/hip_runtime.h>
#include <stdint.h>

typedef unsigned long long u64;

#define BB 8
#define NN 200000
#define CLS 20
#define K_PRE 500
#define MAXDET 300
#define SCORE_TH 0.05f
#define NMS_THR 0.5f

#define NBINS 512
#define CAND_CAP 4096
#define SLABS 25
#define NPER (NN / SLABS)      // 8000
#define FPB (NPER * CLS)       // 160000 floats per block

static constexpr float BINSCALE = (float)NBINS / 0.95f;

// ws layout (bytes)
#define HIST_OFF 0            // 8*20*512*4 = 327680
#define THR_OFF  327680       // 640
#define CCNT_OFF 328320       // 640
#define KSEL_OFF 328960       // 640
#define ZERO_BYTES 329600
#define CAND_OFF 329600       // 160*4096*8 = 5242880
#define CSELK_OFF 5572480     // 160*300*8 = 384000
#define CSELA_OFF 5956480     // 160*300*4 = 192000

__device__ __forceinline__ int score_bin(float s) {
  int b = (int)((s - SCORE_TH) * BINSCALE);
  return b < 0 ? 0 : (b > NBINS - 1 ? NBINS - 1 : b);
}

// Pass 1: per-(b,c) 512-bin histogram of scores > SCORE_TH
__global__ __launch_bounds__(256) void k_hist(const float* __restrict__ cls, int* __restrict__ hist) {
  __shared__ int lh[CLS * NBINS];  // 40KB
  for (int i = threadIdx.x; i < CLS * NBINS; i += 256) lh[i] = 0;
  __syncthreads();
  int slab = blockIdx.x, b = blockIdx.y;
  const float4* base = (const float4*)(cls + ((size_t)b * NN + (size_t)slab * NPER) * CLS);
  for (int t = threadIdx.x; t < FPB / 4; t += 256) {
    float4 v = base[t];
    int i0 = t * 4;
    float vv[4] = {v.x, v.y, v.z, v.w};
#pragma unroll
    for (int k = 0; k < 4; ++k) {
      float s = vv[k];
      if (s > SCORE_TH) {
        int c = (i0 + k) % CLS;
        atomicAdd(&lh[c * NBINS + score_bin(s)], 1);
      }
    }
  }
  __syncthreads();
  int* gh = hist + (size_t)b * CLS * NBINS;
  for (int i = threadIdx.x; i < CLS * NBINS; i += 256) {
    int v = lh[i];
    if (v) atomicAdd(&gh[i], v);
  }
}

// Pick threshold bin: smallest bin with suffix count >= K_PRE (0 if total < K_PRE)
__global__ void k_thr(const int* __restrict__ hist, int* __restrict__ thr) {
  int t = blockIdx.x * blockDim.x + threadIdx.x;
  if (t >= BB * CLS) return;
  const int* h = hist + (size_t)t * NBINS;
  int sum = 0, bin = 0;
  for (int i = NBINS - 1; i >= 0; --i) {
    sum += h[i];
    if (sum >= K_PRE) { bin = i; break; }
  }
  thr[t] = bin;
}

// Pass 2: collect all elements with bin >= threshold (superset of exact top-500)
__global__ __launch_bounds__(256) void k_collect(const float* __restrict__ cls, const int* __restrict__ thr,
                                                 int* __restrict__ ccount, u64* __restrict__ cand) {
  __shared__ int lthr[CLS];
  int slab = blockIdx.x, b = blockIdx.y;
  if (threadIdx.x < CLS) lthr[threadIdx.x] = thr[b * CLS + threadIdx.x];
  __syncthreads();
  const float4* base = (const float4*)(cls + ((size_t)b * NN + (size_t)slab * NPER) * CLS);
  int n0 = slab * NPER;
  for (int t = threadIdx.x; t < FPB / 4; t += 256) {
    float4 v = base[t];
    int i0 = t * 4;
    float vv[4] = {v.x, v.y, v.z, v.w};
#pragma unroll
    for (int k = 0; k < 4; ++k) {
      float s = vv[k];
      if (s > SCORE_TH) {
        int idx = i0 + k;
        int c = idx % CLS;
        if (score_bin(s) >= lthr[c]) {
          int pos = atomicAdd(&ccount[b * CLS + c], 1);
          if (pos < CAND_CAP) {
            int anchor = n0 + idx / CLS;
            // key: score desc, anchor asc  (matches lax.top_k tie-breaking)
            cand[((size_t)(b * CLS + c)) * CAND_CAP + pos] =
                ((u64)__float_as_uint(s) << 32) | (u64)(0xFFFFFFFFu - (unsigned)anchor);
          }
        }
      }
    }
  }
}

// Per-(b,c): exact top-500 via bitonic sort, greedy NMS, per-class cap 300, compacted output
__global__ __launch_bounds__(512) void k_nms(const float* __restrict__ boxes, const int* __restrict__ ccount,
                                             const u64* __restrict__ cand, u64* __restrict__ cselk,
                                             int* __restrict__ csela, int* __restrict__ ksel) {
  __shared__ u64 keys[CAND_CAP];  // 32KB, reused as sup[500][8] bitmatrix
  __shared__ float sx1[K_PRE], sy1[K_PRE], sx2[K_PRE], sy2[K_PRE], sar[K_PRE], ssc[K_PRE];
  __shared__ int sanchor[K_PRE];
  __shared__ u64 keepw[8];
  int bc = blockIdx.x;
  int b = bc / CLS, c = bc % CLS;
  int tid = threadIdx.x;
  int m = ccount[bc]; if (m > CAND_CAP) m = CAND_CAP;
  int nsort = 1024; while (nsort < m) nsort <<= 1;
  for (int i = tid; i < nsort; i += 512) keys[i] = (i < m) ? cand[(size_t)bc * CAND_CAP + i] : 0ULL;
  __syncthreads();
  // bitonic sort, descending
  for (int k = 2; k <= nsort; k <<= 1) {
    for (int j = k >> 1; j > 0; j >>= 1) {
      for (int i = tid; i < nsort; i += 512) {
        int ij = i ^ j;
        if (ij > i) {
          u64 a = keys[i], bv = keys[ij];
          bool up = ((i & k) == 0);
          if (up ? (a < bv) : (a > bv)) { keys[i] = bv; keys[ij] = a; }
        }
      }
      __syncthreads();
    }
  }
  // extract top-500 fragments
  bool val = false;
  if (tid < K_PRE) {
    u64 key = keys[tid];
    float sc = __uint_as_float((unsigned)(key >> 32));
    unsigned anchor = 0xFFFFFFFFu - (unsigned)(key & 0xFFFFFFFFu);
    val = sc > SCORE_TH;
    if (!val || anchor >= NN) anchor = 0;
    float4 bx = *(const float4*)(boxes + ((size_t)b * NN + anchor) * 4);
    sx1[tid] = bx.x; sy1[tid] = bx.y; sx2[tid] = bx.z; sy2[tid] = bx.w;
    sar[tid] = fmaxf(bx.z - bx.x, 0.0f) * fmaxf(bx.w - bx.y, 0.0f);
    ssc[tid] = sc; sanchor[tid] = (int)anchor;
  }
  u64 bm = __ballot(val);
  if ((tid & 63) == 0) keepw[tid >> 6] = bm;
  __syncthreads();
  // zero + build suppression bitmatrix (iou>0.5 & j>i), exact reference fp32 arithmetic
  for (int i = tid; i < K_PRE * 8; i += 512) keys[i] = 0ULL;
  __syncthreads();
  for (int tt = tid; tt < K_PRE * 8; tt += 512) {
    int i = tt >> 3, w = tt & 7;
    float xi1 = sx1[i], yi1 = sy1[i], xi2 = sx2[i], yi2 = sy2[i], ai = sar[i];
    int j0 = w << 6;
    int jend = (j0 + 64 < K_PRE) ? j0 + 64 : K_PRE;
    int jst = (j0 > i + 1) ? j0 : i + 1;
    u64 word = 0;
    for (int j = jst; j < jend; ++j) {
      float iw = fmaxf(fminf(xi2, sx2[j]) - fmaxf(xi1, sx1[j]), 0.0f);
      float ih = fmaxf(fminf(yi2, sy2[j]) - fmaxf(yi1, sy1[j]), 0.0f);
      float inter = iw * ih;
      float denom = fmaxf(ai + sar[j] - inter, 1e-8f);
      if (inter / denom > NMS_THR) word |= 1ULL << (j - j0);
    }
    keys[i * 8 + w] = word;
  }
  __syncthreads();
  // serial greedy sweep (thread 0), unconditional row loads + mask to keep LDS latency pipelined
  if (tid == 0) {
    u64 k0=keepw[0],k1=keepw[1],k2=keepw[2],k3=keepw[3],k4=keepw[4],k5=keepw[5],k6=keepw[6],k7=keepw[7];
#pragma unroll
    for (int w8 = 0; w8 < 8; ++w8) {
      int lim = ((w8 << 6) + 64 <= K_PRE) ? 64 : (K_PRE - (w8 << 6));
      for (int ii = 0; ii < lim; ++ii) {
        u64 kw = w8==0?k0:w8==1?k1:w8==2?k2:w8==3?k3:w8==4?k4:w8==5?k5:w8==6?k6:k7;
        u64 msk = 0ULL - ((kw >> ii) & 1ULL);
        const u64* row = &keys[((w8 << 6) + ii) * 8];
        k0 &= ~(row[0]&msk); k1 &= ~(row[1]&msk); k2 &= ~(row[2]&msk); k3 &= ~(row[3]&msk);
        k4 &= ~(row[4]&msk); k5 &= ~(row[5]&msk); k6 &= ~(row[6]&msk); k7 &= ~(row[7]&msk);
      }
    }
    keepw[0]=k0;keepw[1]=k1;keepw[2]=k2;keepw[3]=k3;keepw[4]=k4;keepw[5]=k5;keepw[6]=k6;keepw[7]=k7;
    int total = __popcll(k0)+__popcll(k1)+__popcll(k2)+__popcll(k3)+__popcll(k4)+__popcll(k5)+__popcll(k6)+__popcll(k7);
    ksel[bc] = total > MAXDET ? MAXDET : total;
  }
  __syncthreads();
  // rank (cumsum-1) and compact survivors with rank < 300
  if (tid < K_PRE) {
    int w = tid >> 6, bpos = tid & 63;
    u64 kw = keepw[w];
    if ((kw >> bpos) & 1ULL) {
      int rank = 0;
      for (int ww = 0; ww < w; ++ww) rank += __popcll(keepw[ww]);
      rank += __popcll(kw & ((1ULL << bpos) - 1ULL));
      if (rank < MAXDET) {
        unsigned flat = (unsigned)(c * K_PRE + tid);  // tie-break: lower flat index first
        cselk[(size_t)bc * MAXDET + rank] = ((u64)__float_as_uint(ssc[tid]) << 32) | (u64)(0xFFFFFFFFu - flat);
        csela[(size_t)bc * MAXDET + rank] = sanchor[tid];
      }
    }
  }
}

// Per-image: 20-way tournament merge of per-class sorted survivor lists -> global top-300
__global__ __launch_bounds__(256) void k_out(const float* __restrict__ boxes, const u64* __restrict__ cselk,
                                             const int* __restrict__ csela, const int* __restrict__ ksel,
                                             float* __restrict__ out) {
  __shared__ u64 skey[CLS][MAXDET];  // 48KB
  __shared__ int skc[CLS];
  __shared__ int winc[MAXDET];
  __shared__ float winsc[MAXDET];
  int b = blockIdx.x, tid = threadIdx.x;
  if (tid < CLS) skc[tid] = ksel[b * CLS + tid];
  __syncthreads();
  for (int t = tid; t < CLS * MAXDET; t += 256) {
    int c = t / MAXDET, p = t % MAXDET;
    skey[c][p] = (p < skc[c]) ? cselk[(size_t)(b * CLS + c) * MAXDET + p] : 0ULL;
  }
  __syncthreads();
  if (tid < 64) {
    int lane = tid;
    u64 cur = 0, nxt = 0; int p = 0, kc = 0;
    if (lane < CLS) {
      kc = skc[lane];
      cur = kc > 0 ? skey[lane][0] : 0ULL;
      nxt = kc > 1 ? skey[lane][1] : 0ULL;
    }
    for (int i = 0; i < MAXDET; ++i) {
      u64 mx = cur;
#pragma unroll
      for (int off = 32; off >= 1; off >>= 1) {
        unsigned hi = __shfl_xor((unsigned)(mx >> 32), off, 64);
        unsigned lo = __shfl_xor((unsigned)(mx & 0xFFFFFFFFu), off, 64);
        u64 o = ((u64)hi << 32) | lo;
        if (o > mx) mx = o;
      }
      if (mx != 0ULL && cur == mx) {  // keys are unique -> exactly one winner
        winc[i] = (lane << 16) | p;
        winsc[i] = __uint_as_float((unsigned)(mx >> 32));
        ++p;
        cur = nxt;
        nxt = (p + 1 < kc) ? skey[lane][p + 1] : 0ULL;
      }
      if (mx == 0ULL && lane == 0) winc[i] = -1;
    }
  }
  __syncthreads();
  for (int i = tid; i < MAXDET; i += 256) {
    int wc = winc[i];
    float4 bx; float sc, lb;
    if (wc < 0) {
      bx = make_float4(-1.f, -1.f, -1.f, -1.f); sc = -1.f; lb = -1.f;
    } else {
      int c = wc >> 16, p = wc & 0xFFFF;
      int anchor = csela[(size_t)(b * CLS + c) * MAXDET + p];
      bx = *(const float4*)(boxes + ((size_t)b * NN + anchor) * 4);
      sc = winsc[i];
      lb = (float)(c - 1);  // reference: out_labels = fl - 1
    }
    *(float4*)(out + ((size_t)b * MAXDET + i) * 4) = bx;
    out[BB * MAXDET * 4 + b * MAXDET + i] = sc;
    out[BB * MAXDET * 4 + BB * MAXDET + b * MAXDET + i] = lb;
  }
}

extern "C" void kernel_launch(void* const* d_in, const int* in_sizes, int n_in,
                              void* d_out, int out_size, void* d_ws, size_t ws_size,
                              hipStream_t stream) {
  (void)in_sizes; (void)n_in; (void)out_size; (void)ws_size;
  const float* boxes = (const float*)d_in[0];
  const float* cls = (const float*)d_in[1];
  float* out = (float*)d_out;
  char* ws = (char*)d_ws;
  int* hist   = (int*)(ws + HIST_OFF);
  int* thr    = (int*)(ws + THR_OFF);
  int* ccount = (int*)(ws + CCNT_OFF);
  int* ksel   = (int*)(ws + KSEL_OFF);
  u64* cand   = (u64*)(ws + CAND_OFF);
  u64* cselk  = (u64*)(ws + CSELK_OFF);
  int* csela  = (int*)(ws + CSELA_OFF);

  hipMemsetAsync(ws, 0, ZERO_BYTES, stream);
  k_hist<<<dim3(SLABS, BB), 256, 0, stream>>>(cls, hist);
  k_thr<<<1, 256, 0, stream>>>(hist, thr);
  k_collect<<<dim3(SLABS, BB), 256, 0, stream>>>(cls, thr, ccount, cand);
  k_nms<<<BB * CLS, 512, 0, stream>>>(boxes, ccount, cand, cselk, csela, ksel);
  k_out<<<BB, 256, 0, stream>>>(boxes, cselk, csela, ksel, out);
}

// Round 2
// 506.606 us; speedup vs baseline: 1.1856x; 1.1856x over previous
//
#include <hip/hip_runtime.h>
#include <stdint.h>

typedef unsigned long long u64;

#define BB 8
#define NN 200000
#define CLS 20
#define K_PRE 500
#define MAXDET 300
#define SCORE_TH 0.05f
#define NMS_THR 0.5f

#define NBINS 512
#define CAND_CAP 4096

// fast path: fixed conservative collect threshold (uniform scores -> ~800/class >> 500)
// exactness for arbitrary inputs preserved by device-side fallback chain below.
#define T_COL 0.996f

// fast collect grid
#define SLABS2 200
#define NPER2 (NN / SLABS2)     // 1000
#define FPB2 (NPER2 * CLS)      // 20000 floats per block

// fallback grid (old histogram path; no-op in practice)
#define SLABS 25
#define NPER (NN / SLABS)       // 8000
#define FPB (NPER * CLS)        // 160000

static constexpr float BINSCALE = (float)NBINS / 0.95f;

// ws layout (bytes)
#define HIST_OFF 0            // 8*20*512*4 = 327680
#define THR_OFF  327680       // 640
#define CCNT_OFF 328320       // 640
#define KSEL_OFF 328960       // 640
#define ZERO_BYTES 329600
#define CAND_OFF 329600       // 160*4096*8 = 5242880
#define CSELK_OFF 5572480     // 160*300*8 = 384000
#define CSELA_OFF 5956480     // 160*300*4 = 192000

__device__ __forceinline__ int score_bin(float s) {
  int b = (int)((s - SCORE_TH) * BINSCALE);
  return b < 0 ? 0 : (b > NBINS - 1 ? NBINS - 1 : b);
}

// ---- fast path: single streaming pass, fixed threshold ----
__global__ __launch_bounds__(256) void k_collect1(const float* __restrict__ cls,
                                                  int* __restrict__ ccount, u64* __restrict__ cand) {
  int slab = blockIdx.x, b = blockIdx.y;
  const float4* base = (const float4*)(cls + ((size_t)b * NN + (size_t)slab * NPER2) * CLS);
  int n0 = slab * NPER2;
  for (int t = threadIdx.x; t < FPB2 / 4; t += 256) {
    float4 v = base[t];
    float mx = fmaxf(fmaxf(v.x, v.y), fmaxf(v.z, v.w));
    if (mx > T_COL) {
      int i0 = t * 4;
      float vv[4] = {v.x, v.y, v.z, v.w};
#pragma unroll
      for (int k = 0; k < 4; ++k) {
        float s = vv[k];
        if (s > T_COL) {
          int idx = i0 + k;
          int c = idx % CLS;
          int anchor = n0 + idx / CLS;
          int pos = atomicAdd(&ccount[b * CLS + c], 1);
          if (pos < CAND_CAP)
            cand[((size_t)(b * CLS + c)) * CAND_CAP + pos] =
                ((u64)__float_as_uint(s) << 32) | (u64)(0xFFFFFFFFu - (unsigned)anchor);
        }
      }
    }
  }
}

// ---- fallback chain (exactness for arbitrary inputs; no-ops for this data) ----
__global__ __launch_bounds__(256) void k_fb_hist(const float* __restrict__ cls,
                                                 const int* __restrict__ ccount, int* __restrict__ hist) {
  int slab = blockIdx.x, b = blockIdx.y;
  // any class of this image deficient/overflowed?
  bool need = false;
  for (int c = threadIdx.x; c < CLS; c += 256) {
    int cnt = ccount[b * CLS + c];
    if (cnt < K_PRE || cnt > CAND_CAP) need = true;
  }
  __shared__ int sneed;
  if (threadIdx.x == 0) sneed = 0;
  __syncthreads();
  if (__ballot(need)) if ((threadIdx.x & 63) == 0) atomicOr(&sneed, 1);
  __syncthreads();
  if (!sneed) return;

  __shared__ int lh[CLS * NBINS];  // 40KB
  for (int i = threadIdx.x; i < CLS * NBINS; i += 256) lh[i] = 0;
  __syncthreads();
  const float4* base = (const float4*)(cls + ((size_t)b * NN + (size_t)slab * NPER) * CLS);
  for (int t = threadIdx.x; t < FPB / 4; t += 256) {
    float4 v = base[t];
    int i0 = t * 4;
    float vv[4] = {v.x, v.y, v.z, v.w};
#pragma unroll
    for (int k = 0; k < 4; ++k) {
      float s = vv[k];
      if (s > SCORE_TH) {
        int c = (i0 + k) % CLS;
        atomicAdd(&lh[c * NBINS + score_bin(s)], 1);
      }
    }
  }
  __syncthreads();
  int* gh = hist + (size_t)b * CLS * NBINS;
  for (int i = threadIdx.x; i < CLS * NBINS; i += 256) {
    int v = lh[i];
    if (v) atomicAdd(&gh[i], v);
  }
}

// per (b,c): if fast-path count OK -> thr = sentinel NBINS; else derive bin from hist, reset ccount
__global__ void k_fb_thr(const int* __restrict__ hist, int* __restrict__ thr, int* __restrict__ ccount) {
  int t = blockIdx.x * blockDim.x + threadIdx.x;
  if (t >= BB * CLS) return;
  int cnt = ccount[t];
  if (cnt >= K_PRE && cnt <= CAND_CAP) { thr[t] = NBINS; return; }
  const int* h = hist + (size_t)t * NBINS;
  int sum = 0, bin = 0;
  for (int i = NBINS - 1; i >= 0; --i) {
    sum += h[i];
    if (sum >= K_PRE) { bin = i; break; }
  }
  thr[t] = bin;
  ccount[t] = 0;
}

__global__ __launch_bounds__(256) void k_fb_collect(const float* __restrict__ cls, const int* __restrict__ thr,
                                                    int* __restrict__ ccount, u64* __restrict__ cand) {
  __shared__ int lthr[CLS];
  __shared__ int sneed;
  int slab = blockIdx.x, b = blockIdx.y;
  if (threadIdx.x == 0) sneed = 0;
  __syncthreads();
  if (threadIdx.x < CLS) {
    int tv = thr[b * CLS + threadIdx.x];
    lthr[threadIdx.x] = tv;
    if (tv < NBINS) atomicOr(&sneed, 1);
  }
  __syncthreads();
  if (!sneed) return;
  const float4* base = (const float4*)(cls + ((size_t)b * NN + (size_t)slab * NPER) * CLS);
  int n0 = slab * NPER;
  for (int t = threadIdx.x; t < FPB / 4; t += 256) {
    float4 v = base[t];
    int i0 = t * 4;
    float vv[4] = {v.x, v.y, v.z, v.w};
#pragma unroll
    for (int k = 0; k < 4; ++k) {
      float s = vv[k];
      if (s > SCORE_TH) {
        int idx = i0 + k;
        int c = idx % CLS;
        if (score_bin(s) >= lthr[c]) {
          int pos = atomicAdd(&ccount[b * CLS + c], 1);
          if (pos < CAND_CAP) {
            int anchor = n0 + idx / CLS;
            cand[((size_t)(b * CLS + c)) * CAND_CAP + pos] =
                ((u64)__float_as_uint(s) << 32) | (u64)(0xFFFFFFFFu - (unsigned)anchor);
          }
        }
      }
    }
  }
}

// ---- per-(b,c): exact top-500 via bitonic sort, greedy NMS, per-class cap, compact ----
__global__ __launch_bounds__(512) void k_nms(const float* __restrict__ boxes, const int* __restrict__ ccount,
                                             const u64* __restrict__ cand, u64* __restrict__ cselk,
                                             int* __restrict__ csela, int* __restrict__ ksel) {
  __shared__ u64 keys[CAND_CAP];  // 32KB, reused as sup[500][8] bitmatrix
  __shared__ float sx1[K_PRE], sy1[K_PRE], sx2[K_PRE], sy2[K_PRE], sar[K_PRE], ssc[K_PRE];
  __shared__ int sanchor[K_PRE];
  __shared__ u64 keepw[8];
  int bc = blockIdx.x;
  int b = bc / CLS, c = bc % CLS;
  int tid = threadIdx.x;
  int m = ccount[bc]; if (m > CAND_CAP) m = CAND_CAP;
  int nsort = 1024; while (nsort < m) nsort <<= 1;
  for (int i = tid; i < nsort; i += 512) keys[i] = (i < m) ? cand[(size_t)bc * CAND_CAP + i] : 0ULL;
  __syncthreads();
  // bitonic sort, descending
  for (int k = 2; k <= nsort; k <<= 1) {
    for (int j = k >> 1; j > 0; j >>= 1) {
      for (int i = tid; i < nsort; i += 512) {
        int ij = i ^ j;
        if (ij > i) {
          u64 a = keys[i], bv = keys[ij];
          bool up = ((i & k) == 0);
          if (up ? (a < bv) : (a > bv)) { keys[i] = bv; keys[ij] = a; }
        }
      }
      __syncthreads();
    }
  }
  // extract top-500 fragments
  bool val = false;
  if (tid < K_PRE) {
    u64 key = keys[tid];
    float sc = __uint_as_float((unsigned)(key >> 32));
    unsigned anchor = 0xFFFFFFFFu - (unsigned)(key & 0xFFFFFFFFu);
    val = sc > SCORE_TH;
    if (!val || anchor >= NN) anchor = 0;
    float4 bx = *(const float4*)(boxes + ((size_t)b * NN + anchor) * 4);
    sx1[tid] = bx.x; sy1[tid] = bx.y; sx2[tid] = bx.z; sy2[tid] = bx.w;
    sar[tid] = fmaxf(bx.z - bx.x, 0.0f) * fmaxf(bx.w - bx.y, 0.0f);
    ssc[tid] = sc; sanchor[tid] = (int)anchor;
  }
  u64 bm = __ballot(val);
  if ((tid & 63) == 0) keepw[tid >> 6] = bm;
  __syncthreads();
  // zero + build suppression bitmatrix (iou>0.5 & j>i), exact reference fp32 arithmetic
  for (int i = tid; i < K_PRE * 8; i += 512) keys[i] = 0ULL;
  __syncthreads();
  for (int tt = tid; tt < K_PRE * 8; tt += 512) {
    int i = tt >> 3, w = tt & 7;
    float xi1 = sx1[i], yi1 = sy1[i], xi2 = sx2[i], yi2 = sy2[i], ai = sar[i];
    int j0 = w << 6;
    int jend = (j0 + 64 < K_PRE) ? j0 + 64 : K_PRE;
    int jst = (j0 > i + 1) ? j0 : i + 1;
    u64 word = 0;
    for (int j = jst; j < jend; ++j) {
      float iw = fmaxf(fminf(xi2, sx2[j]) - fmaxf(xi1, sx1[j]), 0.0f);
      float ih = fmaxf(fminf(yi2, sy2[j]) - fmaxf(yi1, sy1[j]), 0.0f);
      float inter = iw * ih;
      float denom = fmaxf(ai + sar[j] - inter, 1e-8f);
      if (inter / denom > NMS_THR) word |= 1ULL << (j - j0);
    }
    keys[i * 8 + w] = word;
  }
  __syncthreads();
  // greedy sweep: lanes 0-7 of wave 0 own the 8 keep words; row i+1 prefetched
  // while keep-bit for row i travels through one shfl. Critical path ~1 bpermute/iter.
  if (tid < 64) {
    u64 kw = (tid < 8) ? keepw[tid] : 0ULL;
    u64 row = (tid < 8) ? keys[tid] : 0ULL;  // row 0
    for (int i = 0; i < K_PRE; ++i) {
      u64 nrow = (tid < 8 && i + 1 < K_PRE) ? keys[(i + 1) * 8 + tid] : 0ULL;
      int owner = i >> 6;
      unsigned bit = (unsigned)((kw >> (i & 63)) & 1ULL);
      bit = (unsigned)__shfl((int)bit, owner, 64);
      u64 msk = 0ULL - (u64)bit;
      kw &= ~(row & msk);
      row = nrow;
    }
    if (tid < 8) keepw[tid] = kw;
    int cnt = (tid < 8) ? __popcll(kw) : 0;
    cnt += __shfl_xor(cnt, 1, 64);
    cnt += __shfl_xor(cnt, 2, 64);
    cnt += __shfl_xor(cnt, 4, 64);
    if (tid == 0) ksel[bc] = cnt > MAXDET ? MAXDET : cnt;
  }
  __syncthreads();
  // rank (cumsum-1) and compact survivors with rank < 300
  if (tid < K_PRE) {
    int w = tid >> 6, bpos = tid & 63;
    u64 kw = keepw[w];
    if ((kw >> bpos) & 1ULL) {
      int rank = 0;
      for (int ww = 0; ww < w; ++ww) rank += __popcll(keepw[ww]);
      rank += __popcll(kw & ((1ULL << bpos) - 1ULL));
      if (rank < MAXDET) {
        unsigned flat = (unsigned)(c * K_PRE + tid);  // tie-break: lower flat index first
        cselk[(size_t)bc * MAXDET + rank] = ((u64)__float_as_uint(ssc[tid]) << 32) | (u64)(0xFFFFFFFFu - flat);
        csela[(size_t)bc * MAXDET + rank] = sanchor[tid];
      }
    }
  }
}

// ---- per-image: 20-way tournament merge of sorted survivor lists -> global top-300 ----
__global__ __launch_bounds__(256) void k_out(const float* __restrict__ boxes, const u64* __restrict__ cselk,
                                             const int* __restrict__ csela, const int* __restrict__ ksel,
                                             float* __restrict__ out) {
  __shared__ u64 skey[CLS][MAXDET];  // 48KB
  __shared__ int skc[CLS];
  __shared__ int winc[MAXDET];
  __shared__ float winsc[MAXDET];
  int b = blockIdx.x, tid = threadIdx.x;
  if (tid < CLS) skc[tid] = ksel[b * CLS + tid];
  __syncthreads();
  for (int t = tid; t < CLS * MAXDET; t += 256) {
    int c = t / MAXDET, p = t % MAXDET;
    skey[c][p] = (p < skc[c]) ? cselk[(size_t)(b * CLS + c) * MAXDET + p] : 0ULL;
  }
  __syncthreads();
  if (tid < 64) {
    int lane = tid;
    u64 cur = 0, nxt = 0; int p = 0, kc = 0;
    if (lane < CLS) {
      kc = skc[lane];
      cur = kc > 0 ? skey[lane][0] : 0ULL;
      nxt = kc > 1 ? skey[lane][1] : 0ULL;
    }
    for (int i = 0; i < MAXDET; ++i) {
      u64 mx = cur;
#pragma unroll
      for (int off = 32; off >= 1; off >>= 1) {
        unsigned hi = __shfl_xor((unsigned)(mx >> 32), off, 64);
        unsigned lo = __shfl_xor((unsigned)(mx & 0xFFFFFFFFu), off, 64);
        u64 o = ((u64)hi << 32) | lo;
        if (o > mx) mx = o;
      }
      if (mx != 0ULL && cur == mx) {  // keys unique -> exactly one winner
        winc[i] = (lane << 16) | p;
        winsc[i] = __uint_as_float((unsigned)(mx >> 32));
        ++p;
        cur = nxt;
        nxt = (p + 1 < kc) ? skey[lane][p + 1] : 0ULL;
      }
      if (mx == 0ULL && lane == 0) winc[i] = -1;
    }
  }
  __syncthreads();
  for (int i = tid; i < MAXDET; i += 256) {
    int wc = winc[i];
    float4 bx; float sc, lb;
    if (wc < 0) {
      bx = make_float4(-1.f, -1.f, -1.f, -1.f); sc = -1.f; lb = -1.f;
    } else {
      int c = wc >> 16, p = wc & 0xFFFF;
      int anchor = csela[(size_t)(b * CLS + c) * MAXDET + p];
      bx = *(const float4*)(boxes + ((size_t)b * NN + anchor) * 4);
      sc = winsc[i];
      lb = (float)(c - 1);  // reference: out_labels = fl - 1
    }
    *(float4*)(out + ((size_t)b * MAXDET + i) * 4) = bx;
    out[BB * MAXDET * 4 + b * MAXDET + i] = sc;
    out[BB * MAXDET * 4 + BB * MAXDET + b * MAXDET + i] = lb;
  }
}

extern "C" void kernel_launch(void* const* d_in, const int* in_sizes, int n_in,
                              void* d_out, int out_size, void* d_ws, size_t ws_size,
                              hipStream_t stream) {
  (void)in_sizes; (void)n_in; (void)out_size; (void)ws_size;
  const float* boxes = (const float*)d_in[0];
  const float* cls = (const float*)d_in[1];
  float* out = (float*)d_out;
  char* ws = (char*)d_ws;
  int* hist   = (int*)(ws + HIST_OFF);
  int* thr    = (int*)(ws + THR_OFF);
  int* ccount = (int*)(ws + CCNT_OFF);
  int* ksel   = (int*)(ws + KSEL_OFF);
  u64* cand   = (u64*)(ws + CAND_OFF);
  u64* cselk  = (u64*)(ws + CSELK_OFF);
  int* csela  = (int*)(ws + CSELA_OFF);

  hipMemsetAsync(ws, 0, ZERO_BYTES, stream);
  k_collect1<<<dim3(SLABS2, BB), 256, 0, stream>>>(cls, ccount, cand);
  k_fb_hist<<<dim3(SLABS, BB), 256, 0, stream>>>(cls, ccount, hist);
  k_fb_thr<<<1, 256, 0, stream>>>(hist, thr, ccount);
  k_fb_collect<<<dim3(SLABS, BB), 256, 0, stream>>>(cls, thr, ccount, cand);
  k_nms<<<BB * CLS, 512, 0, stream>>>(boxes, ccount, cand, cselk, csela, ksel);
  k_out<<<BB, 256, 0, stream>>>(boxes, cselk, csela, ksel, out);
}